// Round 5
// baseline (144.093 us; speedup 1.0000x reference)
//
#include <hip/hip_runtime.h>
#include <hip/hip_bf16.h>
#include <stdint.h>

typedef __bf16 bf16_t;
typedef __bf16 bf16x8 __attribute__((ext_vector_type(8)));
typedef __bf16 bf16x4 __attribute__((ext_vector_type(4)));
typedef float  f32x4  __attribute__((ext_vector_type(4)));

#define DIM   1024
#define BATCH 8
#define NTOK  (BATCH * DIM)   /* 8192 */
#define SCALE 0.03125f        /* 1/sqrt(1024) */

// ---------------- f32 -> bf16 convert (vectorized) ----------------
__global__ void k_cvt(const float* __restrict__ in, bf16_t* __restrict__ out, int n4) {
    int i = blockIdx.x * blockDim.x + threadIdx.x;
    if (i < n4) {
        const float4 v = reinterpret_cast<const float4*>(in)[i];
        bf16x4 o;
        o.x = (bf16_t)v.x; o.y = (bf16_t)v.y; o.z = (bf16_t)v.z; o.w = (bf16_t)v.w;
        reinterpret_cast<bf16x4*>(out)[i] = o;
    }
}

// ------------- W_eff^T[e][d] = bf16( sum_n w[n][d][e] ) -------------
__global__ void k_weff(const float* __restrict__ w, bf16_t* __restrict__ wt) {
    __shared__ float tile[32][33];
    const int tx = threadIdx.x & 31;
    const int ty = threadIdx.x >> 5;
    const int d0 = blockIdx.x * 32;
    const int e0 = blockIdx.y * 32;
#pragma unroll
    for (int r = 0; r < 4; ++r) {
        const int d = d0 + r * 8 + ty;
        const int e = e0 + tx;
        tile[r * 8 + ty][tx] =
            w[d * 1024 + e] + w[1048576 + d * 1024 + e] + w[2097152 + d * 1024 + e];
    }
    __syncthreads();
#pragma unroll
    for (int r = 0; r < 4; ++r) {
        const int e = e0 + r * 8 + ty;
        const int d = d0 + tx;
        wt[e * 1024 + d] = (bf16_t)tile[tx][r * 8 + ty];
    }
}

// ------------- WqT[d][e] = bf16( Wqkv[e*1024 + d] ) -------------
__global__ void k_trans(const float* __restrict__ in, bf16_t* __restrict__ out) {
    __shared__ float tile[32][33];
    const int tx = threadIdx.x & 31;
    const int ty = threadIdx.x >> 5;
    const int e0 = blockIdx.x * 32;
    const int d0 = blockIdx.y * 32;
#pragma unroll
    for (int r = 0; r < 4; ++r)
        tile[r * 8 + ty][tx] = in[(long)(e0 + r * 8 + ty) * 1024 + d0 + tx];
    __syncthreads();
#pragma unroll
    for (int r = 0; r < 4; ++r)
        out[(long)(d0 + r * 8 + ty) * 1024 + e0 + tx] = (bf16_t)tile[tx][r * 8 + ty];
}

// ------------- bqw[n] = sum_d bq[d] * WeffT[n][d]  (wave-parallel) -------------
__global__ void k_bqw(const float* __restrict__ bq, const bf16_t* __restrict__ wtb,
                      float* __restrict__ bqw) {
    const int wave = threadIdx.x >> 6, lane = threadIdx.x & 63;
    const int n = blockIdx.x * 4 + wave;
    const bf16_t* row = wtb + (long)n * 1024;
    float s = 0.f;
#pragma unroll
    for (int c = 0; c < 2; ++c) {
        const int d0 = (lane + c * 64) * 8;
        const bf16x8 v = *reinterpret_cast<const bf16x8*>(row + d0);
#pragma unroll
        for (int e = 0; e < 8; ++e) s += bq[d0 + e] * (float)v[e];
    }
#pragma unroll
    for (int off = 32; off; off >>= 1) s += __shfl_down(s, off);
    if (lane == 0) bqw[n] = s;
}

// ---------------- 128x128 tile bf16 MFMA GEMM (small B' GEMM only) ------
__global__ __launch_bounds__(256)
void k_gemm128(const bf16_t* __restrict__ A, const bf16_t* __restrict__ B, int K,
               bf16_t* __restrict__ oB)
{
    __shared__ __align__(16) bf16_t As[128 * 32];
    __shared__ __align__(16) bf16_t Bs[128 * 32];

    const int tid  = threadIdx.x;
    const int wave = tid >> 6;
    const int lane = tid & 63;
    const int wr = wave >> 1, wc = wave & 1;
    const int lhi = lane >> 4, llo = lane & 15;

    const int bm = blockIdx.x * 128;
    const int bn = blockIdx.y * 128;

    f32x4 acc[4][4];
    const f32x4 fz = {0.f, 0.f, 0.f, 0.f};
#pragma unroll
    for (int i = 0; i < 4; ++i)
#pragma unroll
        for (int j = 0; j < 4; ++j) acc[i][j] = fz;

    for (int k0 = 0; k0 < K; k0 += 32) {
#pragma unroll
        for (int i = 0; i < 2; ++i) {
            const int c  = wave * 128 + i * 64 + lane;
            const int r  = c >> 2;
            const int cc = (c & 3) << 3;
            const long ga = (long)(bm + r) * K + (k0 + cc);
            const long gb = (long)(bn + r) * K + (k0 + cc);
            const int lbase = (wave * 128 + i * 64) << 3;
            __builtin_amdgcn_global_load_lds(
                (const __attribute__((address_space(1))) uint32_t*)(A + ga),
                (__attribute__((address_space(3))) uint32_t*)(&As[lbase]), 16, 0, 0);
            __builtin_amdgcn_global_load_lds(
                (const __attribute__((address_space(1))) uint32_t*)(B + gb),
                (__attribute__((address_space(3))) uint32_t*)(&Bs[lbase]), 16, 0, 0);
        }
        __syncthreads();

        bf16x8 af[4], bfr[4];
#pragma unroll
        for (int mi = 0; mi < 4; ++mi)
            af[mi] = *reinterpret_cast<const bf16x8*>(&As[(wr * 64 + mi * 16 + llo) * 32 + lhi * 8]);
#pragma unroll
        for (int ni = 0; ni < 4; ++ni)
            bfr[ni] = *reinterpret_cast<const bf16x8*>(&Bs[(wc * 64 + ni * 16 + llo) * 32 + lhi * 8]);
#pragma unroll
        for (int mi = 0; mi < 4; ++mi)
#pragma unroll
            for (int ni = 0; ni < 4; ++ni)
                acc[mi][ni] = __builtin_amdgcn_mfma_f32_16x16x32_bf16(af[mi], bfr[ni], acc[mi][ni], 0, 0, 0);
        __syncthreads();
    }

#pragma unroll
    for (int mi = 0; mi < 4; ++mi) {
        const int r0 = bm + wr * 64 + mi * 16 + lhi * 4;
#pragma unroll
        for (int ni = 0; ni < 4; ++ni) {
            const int cg = bn + wc * 64 + ni * 16 + llo;
            const f32x4 v = acc[mi][ni];
#pragma unroll
            for (int j = 0; j < 4; ++j)
                oB[(long)(r0 + j) * DIM + cg] = (bf16_t)v[j];
        }
    }
}

// ========== ring-3, BK=32, compiler-scheduled K-loop, counted vmcnt ==========
// MODE 1: BM=256,BN=256, grid 384 (32m x 12n), fused qkv projection epilogue.
// MODE 2: BM=128,BN=256, grid 256 (8 batches x 8m x 4n), out += SCALE*acc.
// Per-wave (2M x 4N waves): MODE1 128x64 (ratio 2.67), MODE2 64x64.
// Swizzle: 64B rows paired into 128B lines, phys16B-chunk = logical ^ (line&7)
// (involution; staged linearly from inverse-swizzled global source).
// Sync per K-tile: lgkmcnt(0) [reads retired -> ring slot reuse safe],
// vmcnt(LPT) [tile t+1 landed, t+2 stays in flight], s_barrier. Never drain.
__device__ __forceinline__ int swz(int r, int c) {
    return ((r >> 1) << 7) + (((((r & 1) << 2) | c) ^ ((r >> 1) & 7)) << 4);
}

template<int MODE>
__global__ __launch_bounds__(512, 2)
void k_mm(const bf16_t* __restrict__ A, const bf16_t* __restrict__ Bp,
          const float* __restrict__ bqw, const float* __restrict__ bqkv,
          bf16_t* __restrict__ oQW, bf16_t* __restrict__ oK, float* __restrict__ oF)
{
    constexpr int BM   = (MODE == 1) ? 256 : 128;
    constexpr int MR   = BM / 32;          // m-frags per wave: 8 or 4
    constexpr int LPT  = BM / 128 + 2;     // gloads/thread/tile: 4 or 3
    constexpr int ACH  = BM * 4;           // A 16B-chunks per tile
    constexpr int SLOT = (BM + 256) * 64;  // bytes per ring slot
    constexpr int NTT  = 32;               // K / 32
    __shared__ __align__(16) unsigned char slds[3 * SLOT];

    const int tid  = threadIdx.x;
    const int wave = tid >> 6, lane = tid & 63;
    const int wm = wave >> 2, wn = wave & 3;
    const int llo = lane & 15, lhi = lane >> 4;

    // chunked-XCD swizzled decode (col-fastest so same-XCD blocks share A-panels)
    int bm, bn; long zz;
    if (MODE == 1) {
        const int nw = ((int)blockIdx.x & 7) * 48 + ((int)blockIdx.x >> 3);
        bm = (nw / 12) * 256; bn = (nw % 12) * 256; zz = 0;
    } else {
        const int nw = ((int)blockIdx.x & 7) * 32 + ((int)blockIdx.x >> 3);
        const int wq = nw & 31;
        bm = (wq >> 2) * 128; bn = (wq & 3) * 256;
        zz = (long)(nw >> 5) << 20;
    }

    // per-thread inverse-swizzled staging sources + wave-uniform LDS dests
    const bf16_t* sp[LPT]; int dst[LPT];
#pragma unroll
    for (int j = 0; j < LPT; ++j) {
        const int G = j * 512 + tid;
        const int C = (G < ACH) ? G : G - ACH;
        const int r2 = C >> 3;
        const int u  = (C & 7) ^ (r2 & 7);
        const int r  = (r2 << 1) | (u >> 2);
        const int ce = (u & 3) << 3;
        sp[j] = (G < ACH) ? (A  + zz + (long)(bm + r) * 1024 + ce)
                          : (Bp + zz + (long)(bn + r) * 1024 + ce);
        dst[j] = (j * 512 + wave * 64) << 4;
    }

    f32x4 acc[MR][4];
    const f32x4 fz = {0.f, 0.f, 0.f, 0.f};
#pragma unroll
    for (int i = 0; i < MR; ++i)
#pragma unroll
        for (int j = 0; j < 4; ++j) acc[i][j] = fz;

    auto stage = [&](int tt) {
        unsigned char* sb = &slds[(tt % 3) * SLOT];
        const long ko = (long)tt << 5;
#pragma unroll
        for (int j = 0; j < LPT; ++j)
            __builtin_amdgcn_global_load_lds(
                (const __attribute__((address_space(1))) uint32_t*)(sp[j] + ko),
                (__attribute__((address_space(3))) uint32_t*)(sb + dst[j]), 16, 0, 0);
    };

    stage(0); stage(1);
    asm volatile("s_waitcnt vmcnt(%0)" :: "i"(LPT) : "memory");
    __builtin_amdgcn_s_barrier();

    for (int t = 0; t < NTT; ++t) {
        if (t + 2 < NTT) stage(t + 2);
        const unsigned char* sb = &slds[(t % 3) * SLOT];
        bf16x8 af[MR], bf[4];
#pragma unroll
        for (int mi = 0; mi < MR; ++mi) {
            const int r = wm * (BM / 2) + mi * 16 + llo;
            af[mi] = *reinterpret_cast<const bf16x8*>(sb + swz(r, lhi));
        }
#pragma unroll
        for (int ni = 0; ni < 4; ++ni) {
            const int r = wn * 64 + ni * 16 + llo;
            bf[ni] = *reinterpret_cast<const bf16x8*>(sb + BM * 64 + swz(r, lhi));
        }
#pragma unroll
        for (int mi = 0; mi < MR; ++mi)
#pragma unroll
            for (int ni = 0; ni < 4; ++ni)
                acc[mi][ni] = __builtin_amdgcn_mfma_f32_16x16x32_bf16(
                    af[mi], bf[ni], acc[mi][ni], 0, 0, 0);
        // reads retired before barrier (ring-slot reuse safety)
        asm volatile("s_waitcnt lgkmcnt(0)" ::: "memory");
        if (t + 2 < NTT)      asm volatile("s_waitcnt vmcnt(%0)" :: "i"(LPT) : "memory");
        else if (t + 1 < NTT) asm volatile("s_waitcnt vmcnt(0)" ::: "memory");
        __builtin_amdgcn_s_barrier();
    }

    // ---------------- epilogue ----------------
#pragma unroll
    for (int mi = 0; mi < MR; ++mi) {
        const long r0 = bm + wm * (BM / 2) + mi * 16 + lhi * 4;
#pragma unroll
        for (int ni = 0; ni < 4; ++ni) {
            const int cg = bn + wn * 64 + ni * 16 + llo;
            const f32x4 v = acc[mi][ni];
            if (MODE == 1) {
                const int sec = cg >> 10;
                const int c1  = cg & 1023;
                const float bb = (sec == 0) ? bqw[cg] : bqkv[cg];
#pragma unroll
                for (int j = 0; j < 4; ++j) {
                    const long idx = (r0 + j) * 1024 + c1;
                    const float val = v[j] + bb;
                    if (sec == 0)      oQW[idx] = (bf16_t)val;
                    else if (sec == 1) oK[idx] = (bf16_t)val;
                    else               oF[idx] = val;
                }
            } else {
#pragma unroll
                for (int j = 0; j < 4; ++j) {
                    const long idx = zz + (r0 + j) * 1024 + cg;
                    oF[idx] = oF[idx] + SCALE * v[j];
                }
            }
        }
    }
}

extern "C" void kernel_launch(void* const* d_in, const int* in_sizes, int n_in,
                              void* d_out, int out_size, void* d_ws, size_t ws_size,
                              hipStream_t stream) {
    const float* x    = (const float*)d_in[0];
    const float* Wqkv = (const float*)d_in[1];
    const float* bqkv = (const float*)d_in[2];
    const float* w    = (const float*)d_in[3];
    float* out = (float*)d_out;

    // workspace layout (54 MiB + 64 KiB)
    char* ws = (char*)d_ws;
    bf16_t* xb   = (bf16_t*)(ws);                          // 16 MiB
    bf16_t* wbig = (bf16_t*)(ws + (16l << 20));            // 6 MiB: rows 0:1024 = B', 1024:3072 = Wk,Wv
    float*  bqw  = (float*) (ws + (22l << 20));            // 4 KiB (64 KiB reserved)
    bf16_t* kb   = (bf16_t*)(ws + (22l << 20) + 65536);    // 16 MiB
    bf16_t* qwb  = (bf16_t*)(ws + (38l << 20) + 65536);    // 16 MiB
    bf16_t* wtb  = qwb;              // 2 MiB WeffT (dead before qwb is written)
    bf16_t* wqt  = qwb + 1048576;    // 2 MiB WqT  (dead before qwb is written)
    if (ws_size < (size_t)(54l << 20) + 65536) return;

    // preamble
    k_cvt  <<<8192, 256, 0, stream>>>(x, xb, 2097152);
    k_cvt  <<<2048, 256, 0, stream>>>(Wqkv + 1048576, wbig + 1048576, 524288);
    k_weff <<<dim3(32, 32), 256, 0, stream>>>(w, wtb);
    k_trans<<<dim3(32, 32), 256, 0, stream>>>(Wqkv, wqt);
    k_bqw  <<<256, 256, 0, stream>>>(bqkv, wtb, bqw);

    // B' = WeffT @ WqT^T -> wbig rows [0,1024)
    k_gemm128<<<dim3(8, 8), 256, 0, stream>>>(wtb, wqt, 1024, wbig);

    // fused projection: [qw | k | v] = x @ wbig^T + bias; 384 blocks (256^2 tiles)
    k_mm<1><<<dim3(384), 512, 0, stream>>>(xb, wbig, bqw, bqkv, qwb, kb, out);

    // scores: out += SCALE * qw @ k^T; 256 blocks = 1 exact round (128x256 tiles)
    k_mm<2><<<dim3(256), 512, 0, stream>>>(qwb, kb, nullptr, nullptr,
                                           nullptr, nullptr, out);
}